// Round 4
// baseline (1572.439 us; speedup 1.0000x reference)
//
#include <hip/hip_runtime.h>

typedef __bf16 bf16;
typedef __attribute__((ext_vector_type(4))) __bf16 bf16x4;
typedef __attribute__((ext_vector_type(8))) __bf16 bf16x8;
typedef __attribute__((ext_vector_type(4))) float f32x4;

#define B_ 8
#define TT 12
#define N_ 2048
#define NROW 16384   // B_*N_

__device__ __forceinline__ void gload16(const void* g, void* l) {
  __builtin_amdgcn_global_load_lds((const __attribute__((address_space(1))) void*)g,
                                   (__attribute__((address_space(3))) void*)l, 16, 0, 0);
}

__device__ __forceinline__ float sigmoidf_(float x) {
  x = fminf(fmaxf(x, -30.f), 30.f);
  return 1.f / (1.f + __expf(-x));
}
__device__ __forceinline__ float tanhf_(float x) {
  x = fminf(fmaxf(x, -15.f), 15.f);
  float e = __expf(2.f * x);
  return (e - 1.f) / (e + 1.f);
}

// ---------------------------------------------------------------------------
// Phased graph GEMM (T2+T3+T4+T5). C[m=node-row, chan] partials, 4 K-slabs.
//   part16 layout (fragment-native): [s][mb][wid][mi*NI+ni][lane][4j] bf16
// BM=256, BN=128(gate)/64(cand), BK=64, 512 thr = 8 waves, 3-buffer LDS.
// Stage loads use pre-swizzled GLOBAL source (chunk c ^= row&7) so linear
// global_load_lds produces the swizzled LDS layout; ds_read applies same XOR.
// ---------------------------------------------------------------------------
template<int BN, int WM, int WN>
__global__ __launch_bounds__(512)
void graph_gemm8(const bf16* __restrict__ A16, const bf16* __restrict__ G16,
                 const bf16* __restrict__ U1, const bf16* __restrict__ U2,
                 bf16* __restrict__ part16)
{
  constexpr int MI = (256 / WM) / 16;      // A-frags per wave (8 gate / 4 cand)
  constexpr int NI = (BN / WN) / 16;       // B-frags per wave (2)
  constexpr int ATILE = 256 * 64;          // 32 KB
  constexpr int BTILE = BN * 64;           // 16/8 KB
  constexpr int AISS = 4;                  // 8KB stage issues for A
  constexpr int BISS = BN / 64;            // 2 / 1
  constexpr int LPT = AISS + BISS;         // loads per tile per thread (6 / 5)
  __shared__ bf16 sA[3][ATILE];
  __shared__ bf16 sB[3][BTILE];

  const int tid = threadIdx.x;
  const int lane = tid & 63, wid = tid >> 6;
  const int lr = lane & 15, lq = lane >> 4;
  const int wm = (wid / WN) * (256 / WM);
  const int wn = (wid % WN) * (BN / WN);

  const int mb = blockIdx.x;               // 0..63  (b = mb>>3, node slab = (mb&7)*256)
  const int s  = blockIdx.y;               // 0..3
  const int b  = mb >> 3;
  const int r0 = (mb & 7) * 256;
  const bf16* mat = (s < 2 ? A16 : G16);
  const int kbase = (s & 1) * 1024;
  const bf16* Uc  = (s < 2 ? U1 : U2);

  // staging source pointers (pre-swizzled chunk)
  const int cA = (tid & 7) ^ ((tid >> 3) & 7);
  const bf16* pA = mat + (long)(r0 + (tid >> 3)) * 2048 + kbase + cA * 8;
  const bf16* pB = Uc + (long)(tid >> 3) * (long)NROW + (long)b * 2048 + kbase + cA * 8;

  // swizzled ds_read offsets (elems)
  const int aoff0 = (wm + lr) * 64 + ((lq) ^ (lr & 7)) * 8;
  const int aoff1 = (wm + lr) * 64 + ((4 + lq) ^ (lr & 7)) * 8;
  const int boff0 = (wn + lr) * 64 + ((lq) ^ (lr & 7)) * 8;
  const int boff1 = (wn + lr) * 64 + ((4 + lq) ^ (lr & 7)) * 8;

  f32x4 acc[MI][NI] = {};

  auto stage = [&](int bi, int kt, int ii) {
    if (ii < AISS) {
      gload16(pA + (long)ii * 64 * 2048 + kt * 64, &sA[bi][ii * 4096 + tid * 8]);
    } else {
      const int j = ii - AISS;
      gload16(pB + (long)j * 64 * NROW + kt * 64, &sB[bi][j * 4096 + tid * 8]);
    }
  };

  // prologue: tiles 0,1 fully staged/issued
#pragma unroll
  for (int ii = 0; ii < LPT; ++ii) stage(0, 0, ii);
#pragma unroll
  for (int ii = 0; ii < LPT; ++ii) stage(1, 1, ii);
  asm volatile("s_waitcnt vmcnt(%0)" :: "i"(LPT) : "memory");
  __builtin_amdgcn_s_barrier();
  __builtin_amdgcn_sched_barrier(0);

  for (int t = 0; t < 16; ++t) {
    const int cb = t % 3;
    const int pb = (t + 2) % 3;
    const int kt2 = (t + 2) & 15;          // wraparound: tail prefetch is redundant-but-valid

    // ---- phase 0 (kk=0) ----
    {
      bf16x8 af[MI], bv[NI];
#pragma unroll
      for (int mi = 0; mi < MI; ++mi) af[mi] = *(const bf16x8*)&sA[cb][aoff0 + mi * 1024];
#pragma unroll
      for (int ni = 0; ni < NI; ++ni) bv[ni] = *(const bf16x8*)&sB[cb][boff0 + ni * 1024];
      stage(pb, kt2, 0); stage(pb, kt2, 1); stage(pb, kt2, 2);
      __builtin_amdgcn_s_barrier();
      __builtin_amdgcn_sched_barrier(0);
      __builtin_amdgcn_s_setprio(1);
#pragma unroll
      for (int mi = 0; mi < MI; ++mi)
#pragma unroll
        for (int ni = 0; ni < NI; ++ni)
          acc[mi][ni] = __builtin_amdgcn_mfma_f32_16x16x32_bf16(af[mi], bv[ni], acc[mi][ni], 0, 0, 0);
      __builtin_amdgcn_s_setprio(0);
      __builtin_amdgcn_sched_barrier(0);
    }
    // ---- phase 1 (kk=1) ----
    {
      bf16x8 af[MI], bv[NI];
#pragma unroll
      for (int mi = 0; mi < MI; ++mi) af[mi] = *(const bf16x8*)&sA[cb][aoff1 + mi * 1024];
#pragma unroll
      for (int ni = 0; ni < NI; ++ni) bv[ni] = *(const bf16x8*)&sB[cb][boff1 + ni * 1024];
#pragma unroll
      for (int ii = 3; ii < LPT; ++ii) stage(pb, kt2, ii);
      __builtin_amdgcn_s_barrier();
      __builtin_amdgcn_sched_barrier(0);
      __builtin_amdgcn_s_setprio(1);
#pragma unroll
      for (int mi = 0; mi < MI; ++mi)
#pragma unroll
        for (int ni = 0; ni < NI; ++ni)
          acc[mi][ni] = __builtin_amdgcn_mfma_f32_16x16x32_bf16(af[mi], bv[ni], acc[mi][ni], 0, 0, 0);
      __builtin_amdgcn_s_setprio(0);
      // tile-end: next tile's loads (LPT newest allowed outstanding) must be done
      asm volatile("s_waitcnt vmcnt(%0)" :: "i"(LPT) : "memory");
      __builtin_amdgcn_s_barrier();
      __builtin_amdgcn_sched_barrier(0);
    }
  }

  bf16* pp = part16 + ((((long)s * 64 + mb) * 8 + wid) * (MI * NI)) * 256 + (long)lane * 4;
#pragma unroll
  for (int mi = 0; mi < MI; ++mi)
#pragma unroll
    for (int ni = 0; ni < NI; ++ni) {
      f32x4 v = acc[mi][ni];
      bf16x4 o = {(bf16)v[0], (bf16)v[1], (bf16)v[2], (bf16)v[3]};
      *(bf16x4*)&pp[(mi * NI + ni) * 256] = o;
    }
}

// gate: zr = sigmoid(sum4 part + u0 - u2 + bias); chan<64 -> zh16 = z*h ; else r16
__global__ __launch_bounds__(512)
void gate_reduce8(const bf16* __restrict__ part16, const bf16* __restrict__ U0nm,
                  const bf16* __restrict__ U2nm, const float* __restrict__ bias,
                  const float* __restrict__ h_nm, bf16* __restrict__ zh16,
                  bf16* __restrict__ r16)
{
  constexpr long SLAB = (long)64 * 8 * 16 * 256;   // 2,097,152
  const int mb = blockIdx.x, tid = threadIdx.x;
  const int lane = tid & 63, wid = tid >> 6;
  const int lr = lane & 15, lq = lane >> 4;
  const int wm = (wid >> 2) * 128, wn = (wid & 3) * 32;
  const long fbase = (((long)mb * 8 + wid) * 16) * 256 + lane * 4;
#pragma unroll
  for (int mi = 0; mi < 8; ++mi) {
#pragma unroll
    for (int ni = 0; ni < 2; ++ni) {
      const long fo = fbase + (mi * 2 + ni) * 256;
      float sum[4] = {0.f, 0.f, 0.f, 0.f};
#pragma unroll
      for (int s4 = 0; s4 < 4; ++s4) {
        const bf16x4 p = *(const bf16x4*)&part16[fo + s4 * SLAB];
#pragma unroll
        for (int j = 0; j < 4; ++j) sum[j] += (float)p[j];
      }
      const int row0 = mb * 256 + wm + mi * 16 + lq * 4;
      const int chan = wn + ni * 16 + lr;
      const float bb = bias[chan];
#pragma unroll
      for (int j = 0; j < 4; ++j) {
        const long ro = row0 + j;
        const float u0 = (float)U0nm[ro * 128 + chan];
        const float u2 = (float)U2nm[ro * 128 + chan];
        const float zr = sigmoidf_(sum[j] + u0 - u2 + bb);
        if (chan < 64) {
          zh16[ro * 64 + chan] = (bf16)(zr * h_nm[ro * 64 + chan]);
        } else {
          r16[ro * 64 + chan - 64] = (bf16)zr;
        }
      }
    }
  }
}

// cand: hc = tanh(sum4 part + v0 - v2 + bias); h = r*h+(1-r)*hc -> h_nm, inpG[t+1],
// out = x + h, lastout at t==11.
__global__ __launch_bounds__(512)
void cand_reduce8(const bf16* __restrict__ part16, const bf16* __restrict__ V0nm,
                  const bf16* __restrict__ V2nm, const float* __restrict__ bias,
                  const bf16* __restrict__ r16, float* __restrict__ h_nm,
                  bf16* __restrict__ inpG_next, const float* __restrict__ x,
                  float* __restrict__ out, float* __restrict__ lastout, int t)
{
  constexpr long SLAB = (long)64 * 8 * 8 * 256;    // 1,048,576
  const int mb = blockIdx.x, tid = threadIdx.x;
  const int lane = tid & 63, wid = tid >> 6;
  const int lr = lane & 15, lq = lane >> 4;
  const int wm = (wid >> 1) * 64, wn = (wid & 1) * 32;
  const long fbase = (((long)mb * 8 + wid) * 8) * 256 + lane * 4;
#pragma unroll
  for (int mi = 0; mi < 4; ++mi) {
#pragma unroll
    for (int ni = 0; ni < 2; ++ni) {
      const long fo = fbase + (mi * 2 + ni) * 256;
      float sum[4] = {0.f, 0.f, 0.f, 0.f};
#pragma unroll
      for (int s4 = 0; s4 < 4; ++s4) {
        const bf16x4 p = *(const bf16x4*)&part16[fo + s4 * SLAB];
#pragma unroll
        for (int j = 0; j < 4; ++j) sum[j] += (float)p[j];
      }
      const int row0 = mb * 256 + wm + mi * 16 + lq * 4;
      const int chan = wn + ni * 16 + lr;
      const float bb = bias[chan];
#pragma unroll
      for (int j = 0; j < 4; ++j) {
        const long ro = row0 + j;
        const float v0 = (float)V0nm[ro * 64 + chan];
        const float v2 = (float)V2nm[ro * 64 + chan];
        const float hc = tanhf_(sum[j] + v0 - v2 + bb);
        const float rv = (float)r16[ro * 64 + chan];
        const float ho = h_nm[ro * 64 + chan];
        const float hn = rv * ho + (1.f - rv) * hc;
        h_nm[ro * 64 + chan] = hn;
        if (inpG_next) inpG_next[ro * 128 + 64 + chan] = (bf16)hn;
        const int bb2 = (int)(ro >> 11), n = (int)(ro & 2047);
        const long xo = ((long)(bb2 * TT + t) * N_ + n) * 64 + chan;
        out[xo] = x[xo] + hn;
        if (t == TT - 1) lastout[ro * 64 + chan] = hn;
      }
    }
  }
}

struct WModes {
  bf16* cm[6]; int cmr[6];     // channel-major dst: cm[(cmr+rowl)*NROW + node]
  bf16* nm[6]; int nmc[6];     // node-major dst:    nm[node*nmpitch + nmc + rowl]
  int nmpitch;
};

// C[M,16384] = P[M,128] @ Bt^T. Bt row (node) composite: k<64 from bt0 (pitch 128),
// k>=64 from bt1 (pitch1, +boff1). BM=64, BN=128, BK=32, 4 waves (2x2), wave 32x64.
__global__ __launch_bounds__(256)
void wgemm(const bf16* __restrict__ P,
           const bf16* __restrict__ bt0, const bf16* __restrict__ bt1,
           int pitch1, int boff1, WModes md)
{
  __shared__ bf16 lsA[2][64 * 32];
  __shared__ bf16 lsB[2][128 * 32];
  __shared__ bf16 lsT[128][72];
  const int tid = threadIdx.x;
  const int m0 = blockIdx.y * 64;
  const int n0 = blockIdx.x * 128;
  const int lane = tid & 63, wid = tid >> 6;
  const int wm = (wid >> 1) * 32, wn = (wid & 1) * 64;
  const int lr = lane & 15, lq = lane >> 4;
  f32x4 acc[2][4] = {};

  const int ar = tid >> 2, akc = (tid & 3) * 8;

  for (int kt = 0; kt < 4; ++kt) {
    const int buf = kt & 1;
    if (kt == 0) {
      gload16(P + (long)(m0 + ar) * 128 + akc, &lsA[0][tid * 8]);
#pragma unroll
      for (int i = 0; i < 2; ++i) {
        const int idx = tid + i * 256;
        const int row = idx >> 2, kc = (idx & 3) * 8;
        const bf16* src = (kc < 64) ? bt0 + (long)(n0 + row) * 128 + kc
                                    : bt1 + (long)(n0 + row) * pitch1 + kc + boff1;
        gload16(src, &lsB[0][idx * 8]);
      }
    }
    __syncthreads();
    if (kt < 3) {
      const int nb = (kt + 1) & 1;
      const int k = (kt + 1) * 32 + akc;
      gload16(P + (long)(m0 + ar) * 128 + k, &lsA[nb][tid * 8]);
#pragma unroll
      for (int i = 0; i < 2; ++i) {
        const int idx = tid + i * 256;
        const int row = idx >> 2, kb = (kt + 1) * 32 + (idx & 3) * 8;
        const bf16* src = (kb < 64) ? bt0 + (long)(n0 + row) * 128 + kb
                                    : bt1 + (long)(n0 + row) * pitch1 + kb + boff1;
        gload16(src, &lsB[nb][idx * 8]);
      }
    }
    bf16x8 af[2], bfr[4];
#pragma unroll
    for (int mi = 0; mi < 2; ++mi)
      af[mi] = *(const bf16x8*)&lsA[buf][(wm + mi * 16 + lr) * 32 + lq * 8];
#pragma unroll
    for (int ni = 0; ni < 4; ++ni)
      bfr[ni] = *(const bf16x8*)&lsB[buf][(wn + ni * 16 + lr) * 32 + lq * 8];
#pragma unroll
    for (int mi = 0; mi < 2; ++mi)
#pragma unroll
      for (int ni = 0; ni < 4; ++ni)
        acc[mi][ni] = __builtin_amdgcn_mfma_f32_16x16x32_bf16(af[mi], bfr[ni], acc[mi][ni], 0, 0, 0);
    __syncthreads();
  }

  const int y = blockIdx.y;
  bf16* cm = md.cm[y];
  bf16* nm = md.nm[y];
  if (cm) {
    const int r0 = md.cmr[y];
#pragma unroll
    for (int mi = 0; mi < 2; ++mi)
#pragma unroll
      for (int ni = 0; ni < 4; ++ni) {
        f32x4 v = acc[mi][ni];
        const int col = n0 + wn + ni * 16 + lr;
#pragma unroll
        for (int j = 0; j < 4; ++j)
          cm[(long)(r0 + wm + mi * 16 + lq * 4 + j) * NROW + col] = (bf16)v[j];
      }
  }
  if (nm) {
#pragma unroll
    for (int mi = 0; mi < 2; ++mi)
#pragma unroll
      for (int ni = 0; ni < 4; ++ni) {
        f32x4 v = acc[mi][ni];
        const int cl = wn + ni * 16 + lr;
        const int rl = wm + mi * 16 + lq * 4;
        bf16x4 pk = {(bf16)v[0], (bf16)v[1], (bf16)v[2], (bf16)v[3]};
        *(bf16x4*)&lsT[cl][rl] = pk;
      }
    __syncthreads();
    const int c0 = md.nmc[y], pit = md.nmpitch;
#pragma unroll
    for (int i = 0; i < 4; ++i) {
      const int idx = tid + i * 256;
      const int node = idx >> 3, c8 = idx & 7;
      bf16x8 o = *(bf16x8*)&lsT[node][c8 * 8];
      *(bf16x8*)&nm[(long)(n0 + node) * pit + c0 + c8 * 8] = o;
    }
  }
}

// x-halves of inpG for all t
__global__ __launch_bounds__(256)
void pack_x_all(const float* __restrict__ x, bf16* __restrict__ inpG)
{
  const int idx = blockIdx.x * 256 + threadIdx.x;   // 12*16384*8
  const int t = idx >> 17, rem = idx & 131071;
  const int row = rem >> 3, c8 = rem & 7;
  const int b = row >> 11, n = row & 2047;
  const float* src = &x[((long)(b * TT + t) * N_ + n) * 64 + c8 * 8];
  const float4 v0 = *(const float4*)&src[0];
  const float4 v1 = *(const float4*)&src[4];
  bf16x8 o = {(bf16)v0.x, (bf16)v0.y, (bf16)v0.z, (bf16)v0.w,
              (bf16)v1.x, (bf16)v1.y, (bf16)v1.z, (bf16)v1.w};
  *(bf16x8*)&inpG[((long)t * NROW + row) * 128 + c8 * 8] = o;
}

// h_nm = s0 ; inpG[0] h-half = bf16(s0)
__global__ __launch_bounds__(256)
void init_h0(const float* __restrict__ s0, float* __restrict__ h_nm,
             bf16* __restrict__ inpG0)
{
  const int idx = blockIdx.x * 256 + threadIdx.x;   // 16384*16
  const long row = idx >> 4;
  const int c4 = (idx & 15) * 4;
  const float4 v = *(const float4*)&s0[row * 64 + c4];
  *(float4*)&h_nm[row * 64 + c4] = v;
  bf16x4 o = {(bf16)v.x, (bf16)v.y, (bf16)v.z, (bf16)v.w};
  *(bf16x4*)&inpG0[row * 128 + 64 + c4] = o;
}

__global__ __launch_bounds__(256)
void cvt_bf16(const float* __restrict__ in, bf16* __restrict__ out, long n4)
{
  long i = (long)blockIdx.x * 256 + threadIdx.x;
  const long step = (long)gridDim.x * 256;
  for (; i < n4; i += step) {
    const float4 v = ((const float4*)in)[i];
    bf16x4 o = {(bf16)v.x, (bf16)v.y, (bf16)v.z, (bf16)v.w};
    ((bf16x4*)out)[i] = o;
  }
}

__global__ __launch_bounds__(256)
void transpose_bf(const bf16* __restrict__ in, bf16* __restrict__ out)
{
  __shared__ bf16 t[64][72];
  const int r0 = blockIdx.y * 64, c0 = blockIdx.x * 64, tid = threadIdx.x;
#pragma unroll
  for (int i = 0; i < 2; ++i) {
    const int pos = tid + i * 256;
    const int r = pos >> 3, c8 = pos & 7;
    const bf16x8 v = *(const bf16x8*)&in[((long)(r0 + r) << 11) + c0 + c8 * 8];
    *(bf16x8*)&t[r][c8 * 8] = v;
  }
  __syncthreads();
#pragma unroll
  for (int i = 0; i < 2; ++i) {
    const int pos = tid + i * 256;
    const int c = pos >> 3, r8 = pos & 7;
    bf16x8 o;
#pragma unroll
    for (int j = 0; j < 8; ++j) o[j] = t[r8 * 8 + j][c];
    *(bf16x8*)&out[((long)(c0 + c) << 11) + r0 + r8 * 8] = o;
  }
}

// G16 = bf16(2 * A@A): C[n,j] = 2*sum_m A16[n,m]*At16[j,m]
__global__ __launch_bounds__(256)
void gemm_sq(const bf16* __restrict__ P, const bf16* __restrict__ Bt,
             bf16* __restrict__ Gout)
{
  __shared__ bf16 lsA[2][64 * 32];
  __shared__ bf16 lsB[2][128 * 32];
  const int tid = threadIdx.x;
  const int m0 = blockIdx.y * 64;
  const int n0 = blockIdx.x * 128;
  const int lane = tid & 63, wid = tid >> 6;
  const int wm = (wid >> 1) * 32, wn = (wid & 1) * 64;
  const int lr = lane & 15, lq = lane >> 4;
  f32x4 acc[2][4] = {};
  const int arow = tid >> 2, akc = (tid & 3) * 8;
  const long aoff = ((long)(m0 + arow) << 11) + akc;
  const long boff0 = ((long)(n0 + arow) << 11) + akc;
  const long boff1 = ((long)(n0 + arow + 64) << 11) + akc;
  gload16(P + aoff, &lsA[0][tid * 8]);
  gload16(Bt + boff0, &lsB[0][tid * 8]);
  gload16(Bt + boff1, &lsB[0][(tid + 256) * 8]);
  for (int kt = 0; kt < 64; ++kt) {
    __syncthreads();
    if (kt < 63) {
      const int nb = (kt + 1) & 1;
      const long k = (long)(kt + 1) * 32;
      gload16(P + aoff + k, &lsA[nb][tid * 8]);
      gload16(Bt + boff0 + k, &lsB[nb][tid * 8]);
      gload16(Bt + boff1 + k, &lsB[nb][(tid + 256) * 8]);
    }
    const int cb = kt & 1;
    bf16x8 af[2], bfr[4];
#pragma unroll
    for (int mi = 0; mi < 2; ++mi)
      af[mi] = *(const bf16x8*)&lsA[cb][(wm + mi * 16 + lr) * 32 + lq * 8];
#pragma unroll
    for (int ni = 0; ni < 4; ++ni)
      bfr[ni] = *(const bf16x8*)&lsB[cb][(wn + ni * 16 + lr) * 32 + lq * 8];
#pragma unroll
    for (int mi = 0; mi < 2; ++mi)
#pragma unroll
      for (int ni = 0; ni < 4; ++ni)
        acc[mi][ni] = __builtin_amdgcn_mfma_f32_16x16x32_bf16(af[mi], bfr[ni], acc[mi][ni], 0, 0, 0);
  }
#pragma unroll
  for (int mi = 0; mi < 2; ++mi)
#pragma unroll
    for (int ni = 0; ni < 4; ++ni) {
      f32x4 v = acc[mi][ni];
      const int col = n0 + wn + ni * 16 + lr;
#pragma unroll
      for (int j = 0; j < 4; ++j)
        Gout[((long)(m0 + wm + mi * 16 + lq * 4 + j) << 11) + col] = (bf16)(2.f * v[j]);
    }
}

// Wgt[(k*128+o)][c] = Wg[k][c][o];  Wct[(k*64+o)][c] = Wc[k][c][o]
__global__ __launch_bounds__(256)
void cvt_w(const float* __restrict__ Wg, const float* __restrict__ Wc,
           bf16* __restrict__ Wgt, bf16* __restrict__ Wct)
{
  const int tid0 = blockIdx.x * 256 + threadIdx.x;
  const int step = gridDim.x * 256;
  for (int i = tid0; i < 3 * 128 * 128; i += step) {
    const int k = i >> 14, o = (i >> 7) & 127, c = i & 127;
    Wgt[i] = (bf16)Wg[(k << 14) + (c << 7) + o];
  }
  for (int i = tid0; i < 3 * 64 * 128; i += step) {
    const int k = i >> 13, o = (i >> 7) & 63, c = i & 127;
    Wct[i] = (bf16)Wc[(k << 13) + (c << 6) + o];
  }
}

extern "C" void kernel_launch(void* const* d_in, const int* in_sizes, int n_in,
                              void* d_out, int out_size, void* d_ws, size_t ws_size,
                              hipStream_t stream) {
  (void)in_sizes; (void)n_in; (void)out_size; (void)ws_size;
  const float* x   = (const float*)d_in[0];
  const float* s0  = (const float*)d_in[1];
  const float* adj = (const float*)d_in[2];
  const float* Wg  = (const float*)d_in[3];
  const float* bg  = (const float*)d_in[4];
  const float* Wc  = (const float*)d_in[5];
  const float* bc  = (const float*)d_in[6];
  float* out = (float*)d_out;
  float* lastout = out + (long)B_ * TT * N_ * 64;

  char* wp = (char*)d_ws;
  auto alloc = [&](size_t bytes) { char* p = wp; wp += (bytes + 255) & ~(size_t)255; return p; };
  bf16*  A16  = (bf16*)alloc((size_t)N_ * N_ * 2);
  bf16*  At16 = (bf16*)alloc((size_t)N_ * N_ * 2);
  bf16*  G16  = (bf16*)alloc((size_t)N_ * N_ * 2);
  bf16*  Wgt  = (bf16*)alloc((size_t)384 * 128 * 2);
  bf16*  Wct  = (bf16*)alloc((size_t)192 * 128 * 2);
  bf16*  inpG = (bf16*)alloc((size_t)TT * NROW * 128 * 2);   // 48 MB
  bf16*  U0nm = (bf16*)alloc((size_t)NROW * 128 * 2);
  bf16*  U1cm = (bf16*)alloc((size_t)128 * NROW * 2);
  bf16*  U2cm = (bf16*)alloc((size_t)128 * NROW * 2);
  bf16*  U2nm = (bf16*)alloc((size_t)NROW * 128 * 2);
  bf16*  V0nm = (bf16*)alloc((size_t)NROW * 64 * 2);
  bf16*  V1cm = (bf16*)alloc((size_t)64 * NROW * 2);
  bf16*  V2cm = (bf16*)alloc((size_t)64 * NROW * 2);
  bf16*  V2nm = (bf16*)alloc((size_t)NROW * 64 * 2);
  bf16*  zh16 = (bf16*)alloc((size_t)NROW * 64 * 2);
  bf16*  r16  = (bf16*)alloc((size_t)NROW * 64 * 2);
  float* h_nm = (float*)alloc((size_t)NROW * 64 * 4);
  bf16*  part = (bf16*)alloc((size_t)4 * NROW * 128 * 2);    // 16 MB

  cvt_bf16<<<2048, 256, 0, stream>>>(adj, A16, (long)N_ * N_ / 4);
  transpose_bf<<<dim3(32, 32), 256, 0, stream>>>(A16, At16);
  cvt_w<<<64, 256, 0, stream>>>(Wg, Wc, Wgt, Wct);
  gemm_sq<<<dim3(16, 32), 256, 0, stream>>>(A16, At16, G16);
  pack_x_all<<<6144, 256, 0, stream>>>(x, inpG);
  init_h0<<<1024, 256, 0, stream>>>(s0, h_nm, inpG);

  for (int t = 0; t < TT; ++t) {
    bf16* inpG_t = inpG + (size_t)t * NROW * 128;
    // gate W-mult: y: 0,1 -> u0 nm ; 2,3 -> u1 cm ; 4,5 -> u2 cm+nm
    WModes mg{};
    mg.cm[2] = U1cm; mg.cmr[2] = 0;  mg.cm[3] = U1cm; mg.cmr[3] = 64;
    mg.cm[4] = U2cm; mg.cmr[4] = 0;  mg.cm[5] = U2cm; mg.cmr[5] = 64;
    mg.nm[0] = U0nm; mg.nmc[0] = 0;  mg.nm[1] = U0nm; mg.nmc[1] = 64;
    mg.nm[4] = U2nm; mg.nmc[4] = 0;  mg.nm[5] = U2nm; mg.nmc[5] = 64;
    mg.nmpitch = 128;
    wgemm<<<dim3(128, 6), 256, 0, stream>>>(Wgt, inpG_t, inpG_t, 128, 0, mg);
    graph_gemm8<128, 2, 4><<<dim3(64, 4), 512, 0, stream>>>(A16, G16, U1cm, U2cm, part);
    gate_reduce8<<<64, 512, 0, stream>>>(part, U0nm, U2nm, bg, h_nm, zh16, r16);
    // cand W-mult: y: 0 -> v0 nm ; 1 -> v1 cm ; 2 -> v2 cm+nm. h-half from zh16.
    WModes mc{};
    mc.cm[1] = V1cm; mc.cmr[1] = 0;
    mc.cm[2] = V2cm; mc.cmr[2] = 0;
    mc.nm[0] = V0nm; mc.nmc[0] = 0;
    mc.nm[2] = V2nm; mc.nmc[2] = 0;
    mc.nmpitch = 64;
    wgemm<<<dim3(128, 3), 256, 0, stream>>>(Wct, inpG_t, zh16, 64, -64, mc);
    graph_gemm8<64, 4, 2><<<dim3(64, 4), 512, 0, stream>>>(A16, G16, V1cm, V2cm, part);
    cand_reduce8<<<64, 512, 0, stream>>>(part, V0nm, V2nm, bc, r16, h_nm,
                                         (t < TT - 1) ? inpG + (size_t)(t + 1) * NROW * 128 : nullptr,
                                         x, out, lastout, t);
  }
}

// Round 5
// 964.850 us; speedup vs baseline: 1.6297x; 1.6297x over previous
//
#include <hip/hip_runtime.h>

typedef __bf16 bf16;
typedef __attribute__((ext_vector_type(4))) __bf16 bf16x4;
typedef __attribute__((ext_vector_type(8))) __bf16 bf16x8;
typedef __attribute__((ext_vector_type(4))) float f32x4;

#define B_ 8
#define TT 12
#define N_ 2048
#define NROW 16384   // B_*N_

__device__ __forceinline__ void gload16(const void* g, void* l) {
  __builtin_amdgcn_global_load_lds((const __attribute__((address_space(1))) void*)g,
                                   (__attribute__((address_space(3))) void*)l, 16, 0, 0);
}

__device__ __forceinline__ float sigmoidf_(float x) {
  x = fminf(fmaxf(x, -30.f), 30.f);
  return 1.f / (1.f + __expf(-x));
}
__device__ __forceinline__ float tanhf_(float x) {
  x = fminf(fmaxf(x, -15.f), 15.f);
  float e = __expf(2.f * x);
  return (e - 1.f) / (e + 1.f);
}

// ---------------------------------------------------------------------------
// Phased graph GEMM (T2+T3+T4+T5). 4 K-slabs; node-major bf16 partials:
//   part16[s][row][chan]  (row = mb*256+local, chan = 0..BN)
// BM=256, BN=128(gate)/64(cand), BK=64, 512 thr = 8 waves, 3-buffer LDS.
// Stage loads use pre-swizzled GLOBAL source (chunk ^= row&7) so linear
// global_load_lds produces the swizzled LDS layout; ds_read applies same XOR.
// Epilogue: LDS transpose (aliasing sA) -> coalesced node-major store.
// ---------------------------------------------------------------------------
template<int BN, int WM, int WN>
__global__ __launch_bounds__(512)
void graph_gemm8(const bf16* __restrict__ A16, const bf16* __restrict__ G16,
                 const bf16* __restrict__ U1, const bf16* __restrict__ U2,
                 bf16* __restrict__ part16)
{
  constexpr int MI = (256 / WM) / 16;      // A-frags per wave (8 gate / 4 cand)
  constexpr int NI = (BN / WN) / 16;       // B-frags per wave (2)
  constexpr int ATILE = 256 * 64;          // 32 KB
  constexpr int BTILE = BN * 64;           // 16/8 KB
  constexpr int AISS = 4;
  constexpr int BISS = BN / 64;            // 2 / 1
  constexpr int LPT = AISS + BISS;         // 6 / 5
  __shared__ bf16 sA[3][ATILE];
  __shared__ bf16 sB[3][BTILE];

  const int tid = threadIdx.x;
  const int lane = tid & 63, wid = tid >> 6;
  const int lr = lane & 15, lq = lane >> 4;
  const int wm = (wid / WN) * (256 / WM);
  const int wn = (wid % WN) * (BN / WN);

  const int mb = blockIdx.x;               // 0..63
  const int s  = blockIdx.y;               // 0..3
  const int b  = mb >> 3;
  const int r0 = (mb & 7) * 256;
  const bf16* mat = (s < 2 ? A16 : G16);
  const int kbase = (s & 1) * 1024;
  const bf16* Uc  = (s < 2 ? U1 : U2);

  const int cA = (tid & 7) ^ ((tid >> 3) & 7);
  const bf16* pA = mat + (long)(r0 + (tid >> 3)) * 2048 + kbase + cA * 8;
  const bf16* pB = Uc + (long)(tid >> 3) * (long)NROW + (long)b * 2048 + kbase + cA * 8;

  const int aoff0 = (wm + lr) * 64 + ((lq) ^ (lr & 7)) * 8;
  const int aoff1 = (wm + lr) * 64 + ((4 + lq) ^ (lr & 7)) * 8;
  const int boff0 = (wn + lr) * 64 + ((lq) ^ (lr & 7)) * 8;
  const int boff1 = (wn + lr) * 64 + ((4 + lq) ^ (lr & 7)) * 8;

  f32x4 acc[MI][NI] = {};

  auto stage = [&](int bi, int kt, int ii) {
    if (ii < AISS) {
      gload16(pA + (long)ii * 64 * 2048 + kt * 64, &sA[bi][ii * 4096 + tid * 8]);
    } else {
      const int j = ii - AISS;
      gload16(pB + (long)j * 64 * NROW + kt * 64, &sB[bi][j * 4096 + tid * 8]);
    }
  };

#pragma unroll
  for (int ii = 0; ii < LPT; ++ii) stage(0, 0, ii);
#pragma unroll
  for (int ii = 0; ii < LPT; ++ii) stage(1, 1, ii);
  asm volatile("s_waitcnt vmcnt(%0)" :: "i"(LPT) : "memory");
  __builtin_amdgcn_s_barrier();
  __builtin_amdgcn_sched_barrier(0);

  for (int t = 0; t < 16; ++t) {
    const int cb = t % 3;
    const int pb = (t + 2) % 3;
    const int kt2 = (t + 2) & 15;          // wraparound tail prefetch (redundant, valid)

    {
      bf16x8 af[MI], bv[NI];
#pragma unroll
      for (int mi = 0; mi < MI; ++mi) af[mi] = *(const bf16x8*)&sA[cb][aoff0 + mi * 1024];
#pragma unroll
      for (int ni = 0; ni < NI; ++ni) bv[ni] = *(const bf16x8*)&sB[cb][boff0 + ni * 1024];
      stage(pb, kt2, 0); stage(pb, kt2, 1); stage(pb, kt2, 2);
      __builtin_amdgcn_s_barrier();
      __builtin_amdgcn_sched_barrier(0);
      __builtin_amdgcn_s_setprio(1);
#pragma unroll
      for (int mi = 0; mi < MI; ++mi)
#pragma unroll
        for (int ni = 0; ni < NI; ++ni)
          acc[mi][ni] = __builtin_amdgcn_mfma_f32_16x16x32_bf16(af[mi], bv[ni], acc[mi][ni], 0, 0, 0);
      __builtin_amdgcn_s_setprio(0);
      __builtin_amdgcn_sched_barrier(0);
    }
    {
      bf16x8 af[MI], bv[NI];
#pragma unroll
      for (int mi = 0; mi < MI; ++mi) af[mi] = *(const bf16x8*)&sA[cb][aoff1 + mi * 1024];
#pragma unroll
      for (int ni = 0; ni < NI; ++ni) bv[ni] = *(const bf16x8*)&sB[cb][boff1 + ni * 1024];
#pragma unroll
      for (int ii = 3; ii < LPT; ++ii) stage(pb, kt2, ii);
      __builtin_amdgcn_s_barrier();
      __builtin_amdgcn_sched_barrier(0);
      __builtin_amdgcn_s_setprio(1);
#pragma unroll
      for (int mi = 0; mi < MI; ++mi)
#pragma unroll
        for (int ni = 0; ni < NI; ++ni)
          acc[mi][ni] = __builtin_amdgcn_mfma_f32_16x16x32_bf16(af[mi], bv[ni], acc[mi][ni], 0, 0, 0);
      __builtin_amdgcn_s_setprio(0);
      asm volatile("s_waitcnt vmcnt(%0)" :: "i"(LPT) : "memory");
      __builtin_amdgcn_s_barrier();
      __builtin_amdgcn_sched_barrier(0);
    }
  }

  // ---- epilogue: LDS transpose to node-major, coalesced store ----
  __syncthreads();   // per-wave drains own vmcnt (in-flight wraparound stages) + barrier
  constexpr int PITCH = BN + 8;
  bf16* tbuf = &sA[0][0];                  // 256*PITCH*2 <= 96KB, sA+sB dead now
#pragma unroll
  for (int mi = 0; mi < MI; ++mi)
#pragma unroll
    for (int ni = 0; ni < NI; ++ni) {
      f32x4 v = acc[mi][ni];
      const int chan = wn + ni * 16 + lr;
      const int rw0 = wm + mi * 16 + lq * 4;
#pragma unroll
      for (int j = 0; j < 4; ++j)
        tbuf[(rw0 + j) * PITCH + chan] = (bf16)v[j];
    }
  __syncthreads();
  bf16* pout = part16 + ((long)s * NROW + (long)mb * 256) * BN;
  constexpr int C8 = BN / 8;
  constexpr int ITER = 256 * C8 / 512;
#pragma unroll
  for (int i = 0; i < ITER; ++i) {
    const int idx = tid + i * 512;
    const int row = idx / C8, c8 = idx % C8;
    *(bf16x8*)&pout[(long)row * BN + c8 * 8] = *(const bf16x8*)&tbuf[row * PITCH + c8 * 8];
  }
}

// gate: zr = sigmoid(sum4 part + u0 - u2 + bias); chan<64 -> zh16 = z*h ; else r16
__global__ __launch_bounds__(256)
void gate_reduceN(const bf16* __restrict__ part16, const bf16* __restrict__ U0nm,
                  const bf16* __restrict__ U2nm, const float* __restrict__ bias,
                  const float* __restrict__ h_nm, bf16* __restrict__ zh16,
                  bf16* __restrict__ r16)
{
  const long idx = (long)blockIdx.x * 256 + threadIdx.x;  // NROW*16
  const long row = idx >> 4;
  const int ch = (int)(idx & 15) * 8;
  constexpr long SLAB = (long)NROW * 128;
  float sum[8] = {};
#pragma unroll
  for (int s = 0; s < 4; ++s) {
    const bf16x8 p = *(const bf16x8*)&part16[s * SLAB + row * 128 + ch];
#pragma unroll
    for (int j = 0; j < 8; ++j) sum[j] += (float)p[j];
  }
  const bf16x8 u0 = *(const bf16x8*)&U0nm[row * 128 + ch];
  const bf16x8 u2 = *(const bf16x8*)&U2nm[row * 128 + ch];
  float zr[8];
#pragma unroll
  for (int j = 0; j < 8; ++j)
    zr[j] = sigmoidf_(sum[j] + (float)u0[j] - (float)u2[j] + bias[ch + j]);
  if (ch < 64) {
    const float4 h0 = *(const float4*)&h_nm[row * 64 + ch];
    const float4 h1 = *(const float4*)&h_nm[row * 64 + ch + 4];
    bf16x8 o = {(bf16)(zr[0] * h0.x), (bf16)(zr[1] * h0.y), (bf16)(zr[2] * h0.z),
                (bf16)(zr[3] * h0.w), (bf16)(zr[4] * h1.x), (bf16)(zr[5] * h1.y),
                (bf16)(zr[6] * h1.z), (bf16)(zr[7] * h1.w)};
    *(bf16x8*)&zh16[row * 64 + ch] = o;
  } else {
    bf16x8 o = {(bf16)zr[0], (bf16)zr[1], (bf16)zr[2], (bf16)zr[3],
                (bf16)zr[4], (bf16)zr[5], (bf16)zr[6], (bf16)zr[7]};
    *(bf16x8*)&r16[row * 64 + ch - 64] = o;
  }
}

// cand: hc = tanh(sum4 part + v0 - v2 + bias); h = r*h+(1-r)*hc -> h_nm, inpG[t+1],
// out = x + h, lastout at t==11.
__global__ __launch_bounds__(256)
void cand_reduceN(const bf16* __restrict__ part16, const bf16* __restrict__ V0nm,
                  const bf16* __restrict__ V2nm, const float* __restrict__ bias,
                  const bf16* __restrict__ r16, float* __restrict__ h_nm,
                  bf16* __restrict__ inpG_next, const float* __restrict__ x,
                  float* __restrict__ out, float* __restrict__ lastout, int t)
{
  const long idx = (long)blockIdx.x * 256 + threadIdx.x;  // NROW*8
  const long row = idx >> 3;
  const int ch = (int)(idx & 7) * 8;
  constexpr long SLAB = (long)NROW * 64;
  float sum[8] = {};
#pragma unroll
  for (int s = 0; s < 4; ++s) {
    const bf16x8 p = *(const bf16x8*)&part16[s * SLAB + row * 64 + ch];
#pragma unroll
    for (int j = 0; j < 8; ++j) sum[j] += (float)p[j];
  }
  const bf16x8 v0 = *(const bf16x8*)&V0nm[row * 64 + ch];
  const bf16x8 v2 = *(const bf16x8*)&V2nm[row * 64 + ch];
  const bf16x8 rv = *(const bf16x8*)&r16[row * 64 + ch];
  const float4 h0 = *(const float4*)&h_nm[row * 64 + ch];
  const float4 h1 = *(const float4*)&h_nm[row * 64 + ch + 4];
  const float hof[8] = {h0.x, h0.y, h0.z, h0.w, h1.x, h1.y, h1.z, h1.w};
  float hn[8];
#pragma unroll
  for (int j = 0; j < 8; ++j) {
    const float hc = tanhf_(sum[j] + (float)v0[j] - (float)v2[j] + bias[ch + j]);
    const float r = (float)rv[j];
    hn[j] = r * hof[j] + (1.f - r) * hc;
  }
  float4 ho0 = {hn[0], hn[1], hn[2], hn[3]};
  float4 ho1 = {hn[4], hn[5], hn[6], hn[7]};
  *(float4*)&h_nm[row * 64 + ch] = ho0;
  *(float4*)&h_nm[row * 64 + ch + 4] = ho1;
  if (inpG_next) {
    bf16x8 hb = {(bf16)hn[0], (bf16)hn[1], (bf16)hn[2], (bf16)hn[3],
                 (bf16)hn[4], (bf16)hn[5], (bf16)hn[6], (bf16)hn[7]};
    *(bf16x8*)&inpG_next[row * 128 + 64 + ch] = hb;
  }
  const int b = (int)(row >> 11), n = (int)(row & 2047);
  const long xo = ((long)(b * TT + t) * N_ + n) * 64 + ch;
  const float4 x0 = *(const float4*)&x[xo];
  const float4 x1 = *(const float4*)&x[xo + 4];
  float4 o0 = {x0.x + hn[0], x0.y + hn[1], x0.z + hn[2], x0.w + hn[3]};
  float4 o1 = {x1.x + hn[4], x1.y + hn[5], x1.z + hn[6], x1.w + hn[7]};
  *(float4*)&out[xo] = o0;
  *(float4*)&out[xo + 4] = o1;
  if (t == TT - 1) {
    *(float4*)&lastout[row * 64 + ch] = ho0;
    *(float4*)&lastout[row * 64 + ch + 4] = ho1;
  }
}

struct WModes {
  bf16* cm[6]; int cmr[6];     // channel-major dst: cm[(cmr+rowl)*NROW + node]
  bf16* nm[6]; int nmc[6];     // node-major dst:    nm[node*nmpitch + nmc + rowl]
  int nmpitch;
};

// C[M,16384] = P[M,128] @ Bt^T. Bt row (node) composite: k<64 from bt0 (pitch 128),
// k>=64 from bt1 (pitch1, +boff1). BM=64, BN=128, BK=32, 4 waves (2x2), wave 32x64.
__global__ __launch_bounds__(256)
void wgemm(const bf16* __restrict__ P,
           const bf16* __restrict__ bt0, const bf16* __restrict__ bt1,
           int pitch1, int boff1, WModes md)
{
  __shared__ bf16 lsA[2][64 * 32];
  __shared__ bf16 lsB[2][128 * 32];
  __shared__ bf16 lsT[128][72];
  const int tid = threadIdx.x;
  const int m0 = blockIdx.y * 64;
  const int n0 = blockIdx.x * 128;
  const int lane = tid & 63, wid = tid >> 6;
  const int wm = (wid >> 1) * 32, wn = (wid & 1) * 64;
  const int lr = lane & 15, lq = lane >> 4;
  f32x4 acc[2][4] = {};

  const int ar = tid >> 2, akc = (tid & 3) * 8;

  for (int kt = 0; kt < 4; ++kt) {
    const int buf = kt & 1;
    if (kt == 0) {
      gload16(P + (long)(m0 + ar) * 128 + akc, &lsA[0][tid * 8]);
#pragma unroll
      for (int i = 0; i < 2; ++i) {
        const int idx = tid + i * 256;
        const int row = idx >> 2, kc = (idx & 3) * 8;
        const bf16* src = (kc < 64) ? bt0 + (long)(n0 + row) * 128 + kc
                                    : bt1 + (long)(n0 + row) * pitch1 + kc + boff1;
        gload16(src, &lsB[0][idx * 8]);
      }
    }
    __syncthreads();
    if (kt < 3) {
      const int nb = (kt + 1) & 1;
      const int k = (kt + 1) * 32 + akc;
      gload16(P + (long)(m0 + ar) * 128 + k, &lsA[nb][tid * 8]);
#pragma unroll
      for (int i = 0; i < 2; ++i) {
        const int idx = tid + i * 256;
        const int row = idx >> 2, kb = (kt + 1) * 32 + (idx & 3) * 8;
        const bf16* src = (kb < 64) ? bt0 + (long)(n0 + row) * 128 + kb
                                    : bt1 + (long)(n0 + row) * pitch1 + kb + boff1;
        gload16(src, &lsB[nb][idx * 8]);
      }
    }
    bf16x8 af[2], bfr[4];
#pragma unroll
    for (int mi = 0; mi < 2; ++mi)
      af[mi] = *(const bf16x8*)&lsA[buf][(wm + mi * 16 + lr) * 32 + lq * 8];
#pragma unroll
    for (int ni = 0; ni < 4; ++ni)
      bfr[ni] = *(const bf16x8*)&lsB[buf][(wn + ni * 16 + lr) * 32 + lq * 8];
#pragma unroll
    for (int mi = 0; mi < 2; ++mi)
#pragma unroll
      for (int ni = 0; ni < 4; ++ni)
        acc[mi][ni] = __builtin_amdgcn_mfma_f32_16x16x32_bf16(af[mi], bfr[ni], acc[mi][ni], 0, 0, 0);
    __syncthreads();
  }

  const int y = blockIdx.y;
  bf16* cm = md.cm[y];
  bf16* nm = md.nm[y];
  if (cm) {
    const int r0 = md.cmr[y];
#pragma unroll
    for (int mi = 0; mi < 2; ++mi)
#pragma unroll
      for (int ni = 0; ni < 4; ++ni) {
        f32x4 v = acc[mi][ni];
        const int col = n0 + wn + ni * 16 + lr;
#pragma unroll
        for (int j = 0; j < 4; ++j)
          cm[(long)(r0 + wm + mi * 16 + lq * 4 + j) * NROW + col] = (bf16)v[j];
      }
  }
  if (nm) {
#pragma unroll
    for (int mi = 0; mi < 2; ++mi)
#pragma unroll
      for (int ni = 0; ni < 4; ++ni) {
        f32x4 v = acc[mi][ni];
        const int cl = wn + ni * 16 + lr;
        const int rl = wm + mi * 16 + lq * 4;
        bf16x4 pk = {(bf16)v[0], (bf16)v[1], (bf16)v[2], (bf16)v[3]};
        *(bf16x4*)&lsT[cl][rl] = pk;
      }
    __syncthreads();
    const int c0 = md.nmc[y], pit = md.nmpitch;
#pragma unroll
    for (int i = 0; i < 4; ++i) {
      const int idx = tid + i * 256;
      const int node = idx >> 3, c8 = idx & 7;
      bf16x8 o = *(bf16x8*)&lsT[node][c8 * 8];
      *(bf16x8*)&nm[(long)(n0 + node) * pit + c0 + c8 * 8] = o;
    }
  }
}

// x-halves of inpG for all t
__global__ __launch_bounds__(256)
void pack_x_all(const float* __restrict__ x, bf16* __restrict__ inpG)
{
  const int idx = blockIdx.x * 256 + threadIdx.x;   // 12*16384*8
  const int t = idx >> 17, rem = idx & 131071;
  const int row = rem >> 3, c8 = rem & 7;
  const int b = row >> 11, n = row & 2047;
  const float* src = &x[((long)(b * TT + t) * N_ + n) * 64 + c8 * 8];
  const float4 v0 = *(const float4*)&src[0];
  const float4 v1 = *(const float4*)&src[4];
  bf16x8 o = {(bf16)v0.x, (bf16)v0.y, (bf16)v0.z, (bf16)v0.w,
              (bf16)v1.x, (bf16)v1.y, (bf16)v1.z, (bf16)v1.w};
  *(bf16x8*)&inpG[((long)t * NROW + row) * 128 + c8 * 8] = o;
}

// h_nm = s0 ; inpG[0] h-half = bf16(s0)
__global__ __launch_bounds__(256)
void init_h0(const float* __restrict__ s0, float* __restrict__ h_nm,
             bf16* __restrict__ inpG0)
{
  const int idx = blockIdx.x * 256 + threadIdx.x;   // 16384*16
  const long row = idx >> 4;
  const int c4 = (idx & 15) * 4;
  const float4 v = *(const float4*)&s0[row * 64 + c4];
  *(float4*)&h_nm[row * 64 + c4] = v;
  bf16x4 o = {(bf16)v.x, (bf16)v.y, (bf16)v.z, (bf16)v.w};
  *(bf16x4*)&inpG0[row * 128 + 64 + c4] = o;
}

__global__ __launch_bounds__(256)
void cvt_bf16(const float* __restrict__ in, bf16* __restrict__ out, long n4)
{
  long i = (long)blockIdx.x * 256 + threadIdx.x;
  const long step = (long)gridDim.x * 256;
  for (; i < n4; i += step) {
    const float4 v = ((const float4*)in)[i];
    bf16x4 o = {(bf16)v.x, (bf16)v.y, (bf16)v.z, (bf16)v.w};
    ((bf16x4*)out)[i] = o;
  }
}

__global__ __launch_bounds__(256)
void transpose_bf(const bf16* __restrict__ in, bf16* __restrict__ out)
{
  __shared__ bf16 t[64][72];
  const int r0 = blockIdx.y * 64, c0 = blockIdx.x * 64, tid = threadIdx.x;
#pragma unroll
  for (int i = 0; i < 2; ++i) {
    const int pos = tid + i * 256;
    const int r = pos >> 3, c8 = pos & 7;
    const bf16x8 v = *(const bf16x8*)&in[((long)(r0 + r) << 11) + c0 + c8 * 8];
    *(bf16x8*)&t[r][c8 * 8] = v;
  }
  __syncthreads();
#pragma unroll
  for (int i = 0; i < 2; ++i) {
    const int pos = tid + i * 256;
    const int c = pos >> 3, r8 = pos & 7;
    bf16x8 o;
#pragma unroll
    for (int j = 0; j < 8; ++j) o[j] = t[r8 * 8 + j][c];
    *(bf16x8*)&out[((long)(c0 + c) << 11) + r0 + r8 * 8] = o;
  }
}

// G16 = bf16(2 * A@A): C[n,j] = 2*sum_m A16[n,m]*At16[j,m]
__global__ __launch_bounds__(256)
void gemm_sq(const bf16* __restrict__ P, const bf16* __restrict__ Bt,
             bf16* __restrict__ Gout)
{
  __shared__ bf16 lsA[2][64 * 32];
  __shared__ bf16 lsB[2][128 * 32];
  const int tid = threadIdx.x;
  const int m0 = blockIdx.y * 64;
  const int n0 = blockIdx.x * 128;
  const int lane = tid & 63, wid = tid >> 6;
  const int wm = (wid >> 1) * 32, wn = (wid & 1) * 64;
  const int lr = lane & 15, lq = lane >> 4;
  f32x4 acc[2][4] = {};
  const int arow = tid >> 2, akc = (tid & 3) * 8;
  const long aoff = ((long)(m0 + arow) << 11) + akc;
  const long boff0 = ((long)(n0 + arow) << 11) + akc;
  const long boff1 = ((long)(n0 + arow + 64) << 11) + akc;
  gload16(P + aoff, &lsA[0][tid * 8]);
  gload16(Bt + boff0, &lsB[0][tid * 8]);
  gload16(Bt + boff1, &lsB[0][(tid + 256) * 8]);
  for (int kt = 0; kt < 64; ++kt) {
    __syncthreads();
    if (kt < 63) {
      const int nb = (kt + 1) & 1;
      const long k = (long)(kt + 1) * 32;
      gload16(P + aoff + k, &lsA[nb][tid * 8]);
      gload16(Bt + boff0 + k, &lsB[nb][tid * 8]);
      gload16(Bt + boff1 + k, &lsB[nb][(tid + 256) * 8]);
    }
    const int cb = kt & 1;
    bf16x8 af[2], bfr[4];
#pragma unroll
    for (int mi = 0; mi < 2; ++mi)
      af[mi] = *(const bf16x8*)&lsA[cb][(wm + mi * 16 + lr) * 32 + lq * 8];
#pragma unroll
    for (int ni = 0; ni < 4; ++ni)
      bfr[ni] = *(const bf16x8*)&lsB[cb][(wn + ni * 16 + lr) * 32 + lq * 8];
#pragma unroll
    for (int mi = 0; mi < 2; ++mi)
#pragma unroll
      for (int ni = 0; ni < 4; ++ni)
        acc[mi][ni] = __builtin_amdgcn_mfma_f32_16x16x32_bf16(af[mi], bfr[ni], acc[mi][ni], 0, 0, 0);
  }
#pragma unroll
  for (int mi = 0; mi < 2; ++mi)
#pragma unroll
    for (int ni = 0; ni < 4; ++ni) {
      f32x4 v = acc[mi][ni];
      const int col = n0 + wn + ni * 16 + lr;
#pragma unroll
      for (int j = 0; j < 4; ++j)
        Gout[((long)(m0 + wm + mi * 16 + lq * 4 + j) << 11) + col] = (bf16)(2.f * v[j]);
    }
}

// Wgt[(k*128+o)][c] = Wg[k][c][o];  Wct[(k*64+o)][c] = Wc[k][c][o]
__global__ __launch_bounds__(256)
void cvt_w(const float* __restrict__ Wg, const float* __restrict__ Wc,
           bf16* __restrict__ Wgt, bf16* __restrict__ Wct)
{
  const int tid0 = blockIdx.x * 256 + threadIdx.x;
  const int step = gridDim.x * 256;
  for (int i = tid0; i < 3 * 128 * 128; i += step) {
    const int k = i >> 14, o = (i >> 7) & 127, c = i & 127;
    Wgt[i] = (bf16)Wg[(k << 14) + (c << 7) + o];
  }
  for (int i = tid0; i < 3 * 64 * 128; i += step) {
    const int k = i >> 13, o = (i >> 7) & 63, c = i & 127;
    Wct[i] = (bf16)Wc[(k << 13) + (c << 6) + o];
  }
}

extern "C" void kernel_launch(void* const* d_in, const int* in_sizes, int n_in,
                              void* d_out, int out_size, void* d_ws, size_t ws_size,
                              hipStream_t stream) {
  (void)in_sizes; (void)n_in; (void)out_size; (void)ws_size;
  const float* x   = (const float*)d_in[0];
  const float* s0  = (const float*)d_in[1];
  const float* adj = (const float*)d_in[2];
  const float* Wg  = (const float*)d_in[3];
  const float* bg  = (const float*)d_in[4];
  const float* Wc  = (const float*)d_in[5];
  const float* bc  = (const float*)d_in[6];
  float* out = (float*)d_out;
  float* lastout = out + (long)B_ * TT * N_ * 64;

  char* wp = (char*)d_ws;
  auto alloc = [&](size_t bytes) { char* p = wp; wp += (bytes + 255) & ~(size_t)255; return p; };
  bf16*  A16  = (bf16*)alloc((size_t)N_ * N_ * 2);
  bf16*  At16 = (bf16*)alloc((size_t)N_ * N_ * 2);
  bf16*  G16  = (bf16*)alloc((size_t)N_ * N_ * 2);
  bf16*  Wgt  = (bf16*)alloc((size_t)384 * 128 * 2);
  bf16*  Wct  = (bf16*)alloc((size_t)192 * 128 * 2);
  bf16*  inpG = (bf16*)alloc((size_t)TT * NROW * 128 * 2);   // 48 MB
  bf16*  U0nm = (bf16*)alloc((size_t)NROW * 128 * 2);
  bf16*  U1cm = (bf16*)alloc((size_t)128 * NROW * 2);
  bf16*  U2cm = (bf16*)alloc((size_t)128 * NROW * 2);
  bf16*  U2nm = (bf16*)alloc((size_t)NROW * 128 * 2);
  bf16*  V0nm = (bf16*)alloc((size_t)NROW * 64 * 2);
  bf16*  V1cm = (bf16*)alloc((size_t)64 * NROW * 2);
  bf16*  V2cm = (bf16*)alloc((size_t)64 * NROW * 2);
  bf16*  V2nm = (bf16*)alloc((size_t)NROW * 64 * 2);
  bf16*  zh16 = (bf16*)alloc((size_t)NROW * 64 * 2);
  bf16*  r16  = (bf16*)alloc((size_t)NROW * 64 * 2);
  float* h_nm = (float*)alloc((size_t)NROW * 64 * 4);
  bf16*  part = (bf16*)alloc((size_t)4 * NROW * 128 * 2);    // 16 MB

  cvt_bf16<<<2048, 256, 0, stream>>>(adj, A16, (long)N_ * N_ / 4);
  transpose_bf<<<dim3(32, 32), 256, 0, stream>>>(A16, At16);
  cvt_w<<<64, 256, 0, stream>>>(Wg, Wc, Wgt, Wct);
  gemm_sq<<<dim3(16, 32), 256, 0, stream>>>(A16, At16, G16);
  pack_x_all<<<6144, 256, 0, stream>>>(x, inpG);
  init_h0<<<1024, 256, 0, stream>>>(s0, h_nm, inpG);

  for (int t = 0; t < TT; ++t) {
    bf16* inpG_t = inpG + (size_t)t * NROW * 128;
    // gate W-mult: y: 0,1 -> u0 nm ; 2,3 -> u1 cm ; 4,5 -> u2 cm+nm
    WModes mg{};
    mg.cm[2] = U1cm; mg.cmr[2] = 0;  mg.cm[3] = U1cm; mg.cmr[3] = 64;
    mg.cm[4] = U2cm; mg.cmr[4] = 0;  mg.cm[5] = U2cm; mg.cmr[5] = 64;
    mg.nm[0] = U0nm; mg.nmc[0] = 0;  mg.nm[1] = U0nm; mg.nmc[1] = 64;
    mg.nm[4] = U2nm; mg.nmc[4] = 0;  mg.nm[5] = U2nm; mg.nmc[5] = 64;
    mg.nmpitch = 128;
    wgemm<<<dim3(128, 6), 256, 0, stream>>>(Wgt, inpG_t, inpG_t, 128, 0, mg);
    graph_gemm8<128, 2, 4><<<dim3(64, 4), 512, 0, stream>>>(A16, G16, U1cm, U2cm, part);
    gate_reduceN<<<1024, 256, 0, stream>>>(part, U0nm, U2nm, bg, h_nm, zh16, r16);
    // cand W-mult: y: 0 -> v0 nm ; 1 -> v1 cm ; 2 -> v2 cm+nm. h-half from zh16.
    WModes mc{};
    mc.cm[1] = V1cm; mc.cmr[1] = 0;
    mc.cm[2] = V2cm; mc.cmr[2] = 0;
    mc.nm[0] = V0nm; mc.nmc[0] = 0;
    mc.nm[2] = V2nm; mc.nmc[2] = 0;
    mc.nmpitch = 64;
    wgemm<<<dim3(128, 3), 256, 0, stream>>>(Wct, inpG_t, zh16, 64, -64, mc);
    graph_gemm8<64, 4, 2><<<dim3(64, 4), 512, 0, stream>>>(A16, G16, V1cm, V2cm, part);
    cand_reduceN<<<512, 256, 0, stream>>>(part, V0nm, V2nm, bc, r16, h_nm,
                                          (t < TT - 1) ? inpG + (size_t)(t + 1) * NROW * 128 : nullptr,
                                          x, out, lastout, t);
  }
}